// Round 8
// baseline (140.414 us; speedup 1.0000x reference)
//
#include <hip/hip_runtime.h>
#include <math.h>

// Problem constants (fixed by setup_inputs): B=8, N=2048, C=128, TOP_K=512
// Algebraic structure (verified passing since R1):
//  - adj = softmax(relu(GL GL^T)) + I > 0 everywhere  => att == e, GL unused.
//  - e[b,i,j] = leaky_relu(p_i + q_j) monotone in p_i => keep iff
//    (p_i, -i) >= 512th largest; unselected rows => uniform softmax.
//  - exp(leaky_relu(p+q)) separates at q >= -p; sorted-q order =>
//    suffix/prefix sums per row (boundary lo_i).
//  - p = x@(W@a1), q = x@(W@a2) (R12): no h needed for p,q.
//  - R17 linearity: out_i = relu(z_i @ W), z_i = invD*(A*SUX+B*PVX) (kept)
//    or mean_j x_j (unkept); h never materialized.
//
// Journal: R11 111.2 -> R13 106.3 -> R14 138.4 FAILED (cold-HBM GEMV in 16
// blocks) -> R16 104.8 BEST (rank kernel; h-gemm in fused launch) ->
// R17 118.5 REGRESSED: k_out with 132KB LDS = 1 blk/CU = 1 wave/SIMD; the
// z-build gather + z@W gemm ran latency-bound (~16us). Timeline model:
// fills ~82us fixed; kernels+gaps R16 ~23 / R17 ~36.5.
// R18: keep R17 pipeline; fix k_out occupancy: 16 rows/block (grid 1024),
// NO W staging (L2 float4 reads), LDS ~43KB -> 3 blk/CU, 12-16 waves/CU.
// Launch 2 is rank-only (3us vs R16's 10us rank+gemm): net ~-7us vs R16.
// R19: R18 resubmit — round 7 bench was an infra failure ("container failed
//      twice"), no kernel data. Source re-audited: no hang/fault candidates.

#define B_ 8
#define N_ 2048
#define C_ 128
#define TOPK_ 512
#define NCH_ 32      // chunks per batch
#define CL_ 64       // chunk length (NCH_*CL_ == N_)
#define NP1_ 2052    // padded N+stride, multiple of 4

// ---------------- ws layout (floats) ----------------
#define P_OFF    ((size_t)0)
#define Q_OFF    (P_OFF + (size_t)B_*N_)
#define LOK_OFF  (Q_OFF + (size_t)B_*N_)            // ints: lo | keep<<16
#define US_OFF   (LOK_OFF + (size_t)B_*N_)          // sorted u = e^q
#define VS_OFF   (US_OFF + (size_t)B_*N_)           // sorted w = e^{.01q}
#define SRT_OFF  (VS_OFF + (size_t)B_*N_)           // ints: source row
#define SUS_OFF  (SRT_OFF + (size_t)B_*N_)          // B*NP1_ scalar suffix(u)
#define PVS_OFF  (SUS_OFF + (size_t)B_*NP1_)        // B*NP1_ scalar prefix(w)
#define SUX_OFF  (PVS_OFF + (size_t)B_*NP1_)        // B*N*128 suffix(u*x)
#define PVX_OFF  (SUX_OFF + (size_t)B_*N_*128)      // B*N*128 eprefix(w*x)
#define TOTU_OFF (PVX_OFF + (size_t)B_*N_*128)      // B*NCH*128
#define TOTV_OFF (TOTU_OFF + (size_t)B_*NCH_*128)
#define XPART_OFF (TOTV_OFF + (size_t)B_*NCH_*128)  // 256*128 x col partials

// ---------------- K0: p = x@(W a1), q = x@(W a2), xpart ---------- (proven R17)
__global__ __launch_bounds__(256) void k_pq(const float* __restrict__ x,
                                            const float* __restrict__ W,
                                            const float* __restrict__ a,
                                            float* __restrict__ p,
                                            float* __restrict__ q,
                                            float* __restrict__ xpart) {
  __shared__ float al[256];
  __shared__ float wa1[128], wa2[128];
  __shared__ float xps[2][128];
  const int t = threadIdx.x;
  const int r0 = blockIdx.x * 64;
  al[t] = a[t];
  __syncthreads();
  if (t < 128) {
    const float* Wr = W + (size_t)t * 128;
    float s1 = 0.f, s2 = 0.f;
#pragma unroll
    for (int j = 0; j < 128; j += 4) {
      float4 wv = *(const float4*)(Wr + j);
      s1 = fmaf(wv.x, al[j + 0], s1);
      s1 = fmaf(wv.y, al[j + 1], s1);
      s1 = fmaf(wv.z, al[j + 2], s1);
      s1 = fmaf(wv.w, al[j + 3], s1);
      s2 = fmaf(wv.x, al[128 + j + 0], s2);
      s2 = fmaf(wv.y, al[128 + j + 1], s2);
      s2 = fmaf(wv.z, al[128 + j + 2], s2);
      s2 = fmaf(wv.w, al[128 + j + 3], s2);
    }
    wa1[t] = s1; wa2[t] = s2;
  }
  __syncthreads();
  {
    const int row = t >> 2, part = t & 3;   // 4 consecutive lanes per row
    const float* xr = x + (size_t)(r0 + row) * 128 + part * 32;
    const float* w1 = wa1 + part * 32;
    const float* w2 = wa2 + part * 32;
    float sp = 0.f, sq = 0.f;
#pragma unroll
    for (int i = 0; i < 8; ++i) {
      float4 xv = *(const float4*)(xr + 4 * i);
      float4 w1v = *(const float4*)(w1 + 4 * i);
      float4 w2v = *(const float4*)(w2 + 4 * i);
      sp = fmaf(xv.x, w1v.x, sp); sp = fmaf(xv.y, w1v.y, sp);
      sp = fmaf(xv.z, w1v.z, sp); sp = fmaf(xv.w, w1v.w, sp);
      sq = fmaf(xv.x, w2v.x, sq); sq = fmaf(xv.y, w2v.y, sq);
      sq = fmaf(xv.z, w2v.z, sq); sq = fmaf(xv.w, w2v.w, sq);
    }
    sp += __shfl_xor(sp, 1, 64); sp += __shfl_xor(sp, 2, 64);
    sq += __shfl_xor(sq, 1, 64); sq += __shfl_xor(sq, 2, 64);
    if (part == 0) { p[r0 + row] = sp; q[r0 + row] = sq; }
  }
  // x column-sum partials for the unkept-row mean (L1-hot re-read)
  {
    const int cc = t & 127, hh = t >> 7;   // 2 halves x 32 rows
    float s = 0.f;
    for (int r2 = 32 * hh; r2 < 32 * hh + 32; ++r2)
      s += x[(size_t)(r0 + r2) * 128 + cc];
    xps[hh][cc] = s;
  }
  __syncthreads();
  if (t < 128)
    xpart[(size_t)blockIdx.x * 128 + t] = xps[0][t] + xps[1][t];
}

// ---------------- K1: per-row ranks (proven R16/R17) ------------------------
__global__ __launch_bounds__(256) void k_rank(const float* __restrict__ q,
                                              const float* __restrict__ p,
                                              float* __restrict__ u_s,
                                              float* __restrict__ v_s,
                                              int* __restrict__ srt,
                                              int* __restrict__ lok) {
  __shared__ float ql[N_], pl[N_];   // 16 KB
  const int blk = blockIdx.x, t = threadIdx.x;
  const int b = blk >> 5, tile = blk & 31;
  const int i0 = tile * 64;
#pragma unroll
  for (int i = 0; i < 2; ++i) {
    ((float4*)ql)[t + 256 * i] = ((const float4*)(q + (size_t)b * N_))[t + 256 * i];
    ((float4*)pl)[t + 256 * i] = ((const float4*)(p + (size_t)b * N_))[t + 256 * i];
  }
  __syncthreads();
  const int row = t >> 2, s = t & 3;
  const int i = i0 + row;
  const float qi = ql[i], pi = pl[i];
  const float negpi = -pi;
  int qr = 0, lo = 0, pr = 0;
  for (int g = s; g < 512; g += 4) {
    float4 qj = ((const float4*)ql)[g];
    float4 pj = ((const float4*)pl)[g];
    const int j0 = 4 * g;
    qr += (qj.x < qi || (qj.x == qi && (j0 + 0) < i)) ? 1 : 0;
    qr += (qj.y < qi || (qj.y == qi && (j0 + 1) < i)) ? 1 : 0;
    qr += (qj.z < qi || (qj.z == qi && (j0 + 2) < i)) ? 1 : 0;
    qr += (qj.w < qi || (qj.w == qi && (j0 + 3) < i)) ? 1 : 0;
    lo += (qj.x < negpi) ? 1 : 0;
    lo += (qj.y < negpi) ? 1 : 0;
    lo += (qj.z < negpi) ? 1 : 0;
    lo += (qj.w < negpi) ? 1 : 0;
    pr += (pj.x > pi || (pj.x == pi && (j0 + 0) < i)) ? 1 : 0;
    pr += (pj.y > pi || (pj.y == pi && (j0 + 1) < i)) ? 1 : 0;
    pr += (pj.z > pi || (pj.z == pi && (j0 + 2) < i)) ? 1 : 0;
    pr += (pj.w > pi || (pj.w == pi && (j0 + 3) < i)) ? 1 : 0;
  }
  qr += __shfl_xor(qr, 1, 64); qr += __shfl_xor(qr, 2, 64);
  lo += __shfl_xor(lo, 1, 64); lo += __shfl_xor(lo, 2, 64);
  pr += __shfl_xor(pr, 1, 64); pr += __shfl_xor(pr, 2, 64);
  if (s == 0) {
    u_s[(size_t)b * N_ + qr] = __expf(qi);
    v_s[(size_t)b * N_ + qr] = __expf(0.01f * qi);
    srt[(size_t)b * N_ + qr] = i;
    lok[(size_t)b * N_ + i] = lo | ((pr < TOPK_) ? 0x10000 : 0);
  }
}

// ---------------- K2: x-scans (blocks 0..255) + scalar scans (256..263) -----
__global__ __launch_bounds__(256) void k_scan(const float* __restrict__ x,
                                              const float* __restrict__ u_s,
                                              const float* __restrict__ v_s,
                                              const int* __restrict__ srt,
                                              float* __restrict__ SUX,
                                              float* __restrict__ PVX,
                                              float* __restrict__ totU,
                                              float* __restrict__ totV,
                                              float* __restrict__ SUS,
                                              float* __restrict__ PVS) {
  __shared__ float hl[CL_][128];   // 32 KB (chunk blocks: x rows)
  __shared__ float ul[CL_], vl[CL_];
  __shared__ int sl[CL_];
  __shared__ float2 sa[256], sb[256];  // scalar-scan blocks
  const int t = threadIdx.x;
  if (blockIdx.x >= 256) {
    // ---- scalar suffix/prefix scans over sorted u,w (proven R16) ----
    const int b = blockIdx.x - 256;
    float4 ua = ((const float4*)(u_s + (size_t)b * N_))[2 * t];
    float4 ub = ((const float4*)(u_s + (size_t)b * N_))[2 * t + 1];
    float4 wa = ((const float4*)(v_s + (size_t)b * N_))[2 * t];
    float4 wb = ((const float4*)(v_s + (size_t)b * N_))[2 * t + 1];
    float su = ua.x + ua.y + ua.z + ua.w + ub.x + ub.y + ub.z + ub.w;
    float sw = wa.x + wa.y + wa.z + wa.w + wb.x + wb.y + wb.z + wb.w;
    sa[t] = make_float2(su, sw);
    __syncthreads();
    float2* cur = sa; float2* nxt = sb;
    for (int off = 1; off < 256; off <<= 1) {
      float2 vv = cur[t];
      if (t >= off) { float2 o = cur[t - off]; vv.x += o.x; vv.y += o.y; }
      nxt[t] = vv;
      __syncthreads();
      float2* tmp = cur; cur = nxt; nxt = tmp;
    }
    float2 incl = cur[t];
    float2 tot = cur[255];
    float exclU = incl.x - su, exclW = incl.y - sw;
    float s0 = tot.x - exclU;
    float s1 = s0 - ua.x, s2 = s1 - ua.y, s3 = s2 - ua.z;
    float s4 = s3 - ua.w, s5 = s4 - ub.x, s6 = s5 - ub.y, s7 = s6 - ub.z;
    float p0 = exclW;
    float p1 = p0 + wa.x, p2 = p1 + wa.y, p3 = p2 + wa.z;
    float p4 = p3 + wa.w, p5 = p4 + wb.x, p6 = p5 + wb.y, p7 = p6 + wb.z;
    float* Sb = SUS + (size_t)b * NP1_ + 8 * t;
    float* Pb = PVS + (size_t)b * NP1_ + 8 * t;
    *(float4*)(Sb) = make_float4(s0, s1, s2, s3);
    *(float4*)(Sb + 4) = make_float4(s4, s5, s6, s7);
    *(float4*)(Pb) = make_float4(p0, p1, p2, p3);
    *(float4*)(Pb + 4) = make_float4(p4, p5, p6, p7);
    if (t == 255) {
      SUS[(size_t)b * NP1_ + N_] = 0.f;
      PVS[(size_t)b * NP1_ + N_] = tot.y;
    }
    return;
  }
  // ---- chunk-local scans over x rows (proven R13/R17) ----
  const int b = blockIdx.x >> 5, ch = blockIdx.x & 31;
  const int base = b * N_ + ch * CL_;
  if (t < CL_) { ul[t] = u_s[base + t]; vl[t] = v_s[base + t]; sl[t] = srt[base + t]; }
  __syncthreads();
  {
    const int c4 = t & 31, rr = t >> 5;
#pragma unroll
    for (int i = 0; i < 8; ++i) {
      int tt = rr + 8 * i;
      float4 v = *(const float4*)(x + ((size_t)b * N_ + sl[tt]) * 128 + 4 * c4);
      *(float4*)(&hl[tt][4 * c4]) = v;
    }
  }
  __syncthreads();
  if (t < 128) {
    const int c = t;
    float run = 0.f;
    for (int tt = CL_ - 1; tt >= 0; --tt) {
      run = fmaf(ul[tt], hl[tt][c], run);
      SUX[((size_t)(base + tt)) * 128 + c] = run;
    }
    totU[(size_t)(b * NCH_ + ch) * 128 + c] = run;
  } else {
    const int c = t - 128;
    float run2 = 0.f;
    for (int tt = 0; tt < CL_; ++tt) {
      PVX[((size_t)(base + tt)) * 128 + c] = run2;
      run2 = fmaf(vl[tt], hl[tt][c], run2);
    }
    totV[(size_t)(b * NCH_ + ch) * 128 + c] = run2;
  }
}

// ---------------- K3: tables + z build + z@W gemm + relu + store ------------
// 16 rows/block, grid B*128 = 1024 -> 3-4 blocks/CU, 12-16 waves/CU.
// W NOT staged: read float4 from L2 (64KB x 1024 blocks = 64MB L2, ~2us).
__global__ __launch_bounds__(256) void k_out(const float* __restrict__ p,
                                             const int* __restrict__ lok,
                                             const float* __restrict__ SUS,
                                             const float* __restrict__ PVS,
                                             const float* __restrict__ SUX,
                                             const float* __restrict__ PVX,
                                             const float* __restrict__ totU,
                                             const float* __restrict__ totV,
                                             const float* __restrict__ xpart,
                                             const float* __restrict__ W,
                                             float* __restrict__ out) {
  __shared__ float zl[16 * 132];             // 8.4 KB (pad 132)
  __shared__ union {
    struct { float CSU[(NCH_ + 1) * 128]; float CPV[(NCH_ + 1) * 128]; float xm[128]; } tb;
    float res[16 * 129];                     // 8.3 KB (post-gemm reuse)
  } u_;
  __shared__ float A_s[16], B_s[16], invD[16];
  __shared__ int lo_s[16], keep_s[16];
  const int b = blockIdx.x >> 7, tile = blockIdx.x & 127;
  const int t = threadIdx.x;
  const int i0 = tile * 16;
  // cross-chunk tables + x-mean (L2-hot; redundancy across 128 tiles/batch)
  if (t < 128) {
    float ms = 0.f;
#pragma unroll
    for (int j = 0; j < 32; ++j) ms += xpart[(size_t)(b * 32 + j) * 128 + t];
    u_.tb.xm[t] = ms * (1.0f / (float)N_);
    float s = 0.f;
    u_.tb.CSU[NCH_ * 128 + t] = 0.f;
    for (int cc = NCH_ - 1; cc >= 0; --cc) {
      s += totU[(size_t)(b * NCH_ + cc) * 128 + t];
      u_.tb.CSU[cc * 128 + t] = s;
    }
  } else {
    const int c2 = t - 128;
    float s2 = 0.f;
    for (int cc = 0; cc < NCH_; ++cc) {
      u_.tb.CPV[cc * 128 + c2] = s2;
      s2 += totV[(size_t)(b * NCH_ + cc) * 128 + c2];
    }
    u_.tb.CPV[NCH_ * 128 + c2] = s2;
  }
  __syncthreads();
  if (t < 16) {  // per-row scalars (lo/keep from rank kernel)
    float pv = p[b * N_ + i0 + t];
    int lk = lok[(size_t)b * N_ + i0 + t];
    keep_s[t] = (lk >> 16) & 1;
    int lo = lk & 0xFFFF;
    lo_s[t] = lo;
    float A = __expf(pv), Bv = __expf(0.01f * pv);
    A_s[t] = A; B_s[t] = Bv;
    float sus = SUS[(size_t)b * NP1_ + lo];
    float pvs = PVS[(size_t)b * NP1_ + lo];
    invD[t] = 1.0f / fmaf(A, sus, Bv * pvs);
  }
  __syncthreads();
  // z build: z_i[c] = invD*(A*SUXc + B*PVXc) or xm[c]; rows ii = 2m + half
  {
    const int half = t >> 7, c = t & 127;
#pragma unroll
    for (int m = 0; m < 8; ++m) {
      int ii = 2 * m + half;
      float zv;
      if (keep_s[ii]) {
        int lo = lo_s[ii];
        float A = A_s[ii], Bv = B_s[ii];
        float suc, pvc;
        if (lo < N_) {
          int chn = lo >> 6;   // / CL_
          size_t ro = ((size_t)(b * N_ + lo)) * 128;
          suc = SUX[ro + c] + u_.tb.CSU[(chn + 1) * 128 + c];
          pvc = PVX[ro + c] + u_.tb.CPV[chn * 128 + c];
        } else {
          suc = 0.f;
          pvc = u_.tb.CPV[NCH_ * 128 + c];
        }
        zv = fmaf(A, suc, Bv * pvc) * invD[ii];
      } else {
        zv = u_.tb.xm[c];
      }
      zl[ii * 132 + c] = zv;
    }
  }
  __syncthreads();
  // gemm: out_rows = z @ W (16x128 @ 128x128); 1 row x 8 cols per thread
  const int cg = t & 15, row = t >> 4;
  const int c0 = 4 * cg, c1 = 4 * cg + 64;
  float acc[8];
#pragma unroll
  for (int j = 0; j < 8; ++j) acc[j] = 0.f;
  {
    const float4* W4 = (const float4*)W;
#pragma unroll 4
    for (int k = 0; k < 128; ++k) {
      float4 w0 = W4[k * 32 + cg];
      float4 w1 = W4[k * 32 + cg + 16];
      float zv = zl[row * 132 + k];
      acc[0] = fmaf(zv, w0.x, acc[0]);
      acc[1] = fmaf(zv, w0.y, acc[1]);
      acc[2] = fmaf(zv, w0.z, acc[2]);
      acc[3] = fmaf(zv, w0.w, acc[3]);
      acc[4] = fmaf(zv, w1.x, acc[4]);
      acc[5] = fmaf(zv, w1.y, acc[5]);
      acc[6] = fmaf(zv, w1.z, acc[6]);
      acc[7] = fmaf(zv, w1.w, acc[7]);
    }
  }
  __syncthreads();   // tables dead; res aliases them
#pragma unroll
  for (int j = 0; j < 4; ++j) {
    u_.res[row * 129 + c0 + j] = fmaxf(acc[j], 0.f);
    u_.res[row * 129 + c1 + j] = fmaxf(acc[4 + j], 0.f);
  }
  __syncthreads();
  // out[b][c][i] = res[i - i0][c]; 512 float4 stores, 2 passes
#pragma unroll
  for (int pass = 0; pass < 2; ++pass) {
    int idx = pass * 256 + t;
    int cc = idx >> 2;
    int ii4 = (idx & 3) * 4;
    float4 v;
    v.x = u_.res[(ii4 + 0) * 129 + cc];
    v.y = u_.res[(ii4 + 1) * 129 + cc];
    v.z = u_.res[(ii4 + 2) * 129 + cc];
    v.w = u_.res[(ii4 + 3) * 129 + cc];
    *(float4*)(out + ((size_t)(b * C_ + cc)) * N_ + i0 + ii4) = v;
  }
}

extern "C" void kernel_launch(void* const* d_in, const int* in_sizes, int n_in,
                              void* d_out, int out_size, void* d_ws, size_t ws_size,
                              hipStream_t stream) {
  (void)in_sizes; (void)n_in; (void)out_size; (void)ws_size;
  const float* x = (const float*)d_in[0];
  const float* W = (const float*)d_in[1];
  const float* a = (const float*)d_in[2];
  // d_in[3] (GL) is provably unused: adj > 0 everywhere.
  float* out = (float*)d_out;
  float* ws = (float*)d_ws;

  float* p    = ws + P_OFF;
  float* q    = ws + Q_OFF;
  int*   lok  = (int*)(ws + LOK_OFF);
  float* u_s  = ws + US_OFF;
  float* v_s  = ws + VS_OFF;
  int*   srt  = (int*)(ws + SRT_OFF);
  float* SUS  = ws + SUS_OFF;
  float* PVS  = ws + PVS_OFF;
  float* SUX  = ws + SUX_OFF;
  float* PVX  = ws + PVX_OFF;
  float* totU = ws + TOTU_OFF;
  float* totV = ws + TOTV_OFF;
  float* xpart = ws + XPART_OFF;

  k_pq<<<dim3((B_ * N_) / 64), dim3(256), 0, stream>>>(x, W, a, p, q, xpart);
  k_rank<<<dim3(B_ * 32), dim3(256), 0, stream>>>(q, p, u_s, v_s, srt, lok);
  k_scan<<<dim3(256 + B_), dim3(256), 0, stream>>>(x, u_s, v_s, srt, SUX, PVX, totU, totV, SUS, PVS);
  k_out<<<dim3(B_ * 128), dim3(256), 0, stream>>>(p, lok, SUS, PVS, SUX, PVX, totU, totV, xpart, W, out);
}